// Round 9
// baseline (444.824 us; speedup 1.0000x reference)
//
#include <hip/hip_runtime.h>
#include <hip/hip_bf16.h>

typedef __attribute__((ext_vector_type(4))) float f32x4;
typedef __attribute__((ext_vector_type(8))) short s16x8;
typedef __attribute__((address_space(3))) unsigned int lds_uint;
typedef __attribute__((address_space(1))) const unsigned int g_uint;

static __device__ __forceinline__ unsigned short f2b(float f) {
    union { __hip_bfloat16 h; unsigned short u; } c;
    c.h = __float2bfloat16(f);
    return c.u;
}

static __device__ __forceinline__ void async_copy16(const void* gsrc, void* ldst) {
    __builtin_amdgcn_global_load_lds((g_uint*)gsrc, (lds_uint*)ldst, 16, 0, 0);
}

// ---------------- x fp32 -> bf16 ----------------
__global__ __launch_bounds__(256) void cvt_x_kernel(const float* __restrict__ x,
                                                    unsigned short* __restrict__ xb) {
    long i = ((long)blockIdx.x * 256 + threadIdx.x) * 8;
    float4 a = *(const float4*)(x + i);
    float4 b = *(const float4*)(x + i + 4);
    union { unsigned short s[8]; s16x8 v; } o;
    o.s[0] = f2b(a.x); o.s[1] = f2b(a.y); o.s[2] = f2b(a.z); o.s[3] = f2b(a.w);
    o.s[4] = f2b(b.x); o.s[5] = f2b(b.y); o.s[6] = f2b(b.z); o.s[7] = f2b(b.w);
    *(s16x8*)(xb + i) = o.v;
}

// ---------------- W [K,N] fp32 -> Wt [N,K] bf16 (transpose+convert) ----------------
__global__ __launch_bounds__(256) void cvt_wT_kernel(const float* __restrict__ W,
                                                     unsigned short* __restrict__ Wt,
                                                     int K, int N) {
    __shared__ float T[64][65];
    int nbk = K >> 6;
    int bk = blockIdx.x % nbk;
    int bn = blockIdx.x / nbk;
    int t = threadIdx.x;
    int r = t >> 4, c4 = (t & 15) << 2;
#pragma unroll
    for (int rd = 0; rd < 4; ++rd) {
        int row = rd * 16 + r;
        float4 v = *(const float4*)(W + (long)(bk * 64 + row) * N + bn * 64 + c4);
        T[row][c4 + 0] = v.x; T[row][c4 + 1] = v.y;
        T[row][c4 + 2] = v.z; T[row][c4 + 3] = v.w;
    }
    __syncthreads();
#pragma unroll
    for (int rd = 0; rd < 4; ++rd) {
        int nrow = rd * 16 + r;
        union { unsigned short s[4]; unsigned long long u; } o;
#pragma unroll
        for (int j = 0; j < 4; ++j) o.s[j] = f2b(T[c4 + j][nrow]);
        *(unsigned long long*)(Wt + (long)(bn * 64 + nrow) * K + bk * 64 + c4) = o.u;
    }
}

// ---------------- 8-phase 256x256 GEMM, K=1024, B^T form ----------------
template<int OM>
__global__ __launch_bounds__(512) void gemm256_kernel(const unsigned short* __restrict__ A,
                                                      const unsigned short* __restrict__ Bt,
                                                      const float* __restrict__ bias,
                                                      unsigned short* __restrict__ qkb,
                                                      unsigned short* __restrict__ vT,
                                                      float* __restrict__ Cf,
                                                      int ntileN) {
    __shared__ char lds[131072];
    const int tid = threadIdx.x;
    const int w = tid >> 6, wm = w >> 2, wn = w & 3;
    const int l = tid & 63, c = l & 15, g = l >> 4;
    const int cpx = gridDim.x >> 3;
    const int wg = (blockIdx.x & 7) * cpx + (blockIdx.x >> 3);  // bijective: grid%8==0
    const int tm = wg / ntileN, tn = wg % ntileN;
    const long m0 = (long)tm << 8, n0 = (long)tn << 8;
    const int swg = (g ^ ((c >> 1) & 3)) << 4;
    const int ssch = (tid & 3) ^ ((tid >> 3) & 3);
    const int rb = tid >> 2;

    f32x4 acc[8][4];
#pragma unroll
    for (int i = 0; i < 8; ++i)
#pragma unroll
        for (int j = 0; j < 4; ++j) acc[i][j] = (f32x4){0.f, 0.f, 0.f, 0.f};

#define STG(panel, p0, u, kh, isB) do { \
    char* blk_ = lds + ((isB) ? 65536 : 0) + (((((u) & 1) * 2 + (kh))) << 14); \
    const unsigned short* sp_ = (panel) + (u) * 64 + (kh) * 32 + ssch * 8; \
    async_copy16(sp_ + ((p0) + rb) * 1024L, blk_ + tid * 16); \
    async_copy16(sp_ + ((p0) + 128 + rb) * 1024L, blk_ + 8192 + tid * 16); \
} while (0)

    STG(Bt, n0, 0, 0, 1); STG(A, m0, 0, 0, 0); STG(Bt, n0, 0, 1, 1); STG(A, m0, 0, 1, 0);
    STG(Bt, n0, 1, 0, 1); STG(A, m0, 1, 0, 0); STG(Bt, n0, 1, 1, 1);
    asm volatile("s_waitcnt vmcnt(10)");
    __builtin_amdgcn_s_barrier();
    __builtin_amdgcn_sched_barrier(0);

#define PHASE_MFMA(IBASE) \
    __builtin_amdgcn_s_setprio(1); \
    _Pragma("unroll") for (int i_ = 0; i_ < 4; ++i_) \
    _Pragma("unroll") for (int j_ = 0; j_ < 4; ++j_) \
        acc[(IBASE) + i_][j_] = __builtin_amdgcn_mfma_f32_16x16x32_bf16(af[i_], bf[j_], acc[(IBASE) + i_][j_], 0, 0, 0); \
    __builtin_amdgcn_s_setprio(0);

#define GSTEP(s, ST1, ST2, ST3, ST4, VMID, VEND) do { \
    const int buf_ = (s) & 1; \
    const char* LA0 = lds + ((buf_ * 2 + 0) << 14); \
    const char* LA1 = lds + ((buf_ * 2 + 1) << 14); \
    const char* LB0 = lds + 65536 + ((buf_ * 2 + 0) << 14); \
    const char* LB1 = lds + 65536 + ((buf_ * 2 + 1) << 14); \
    s16x8 af[4], bf[4]; \
    _Pragma("unroll") for (int i = 0; i < 4; ++i) af[i] = *(const s16x8*)(LA0 + (wm * 128 + i * 16 + c) * 64 + swg); \
    _Pragma("unroll") for (int j = 0; j < 4; ++j) bf[j] = *(const s16x8*)(LB0 + (wn * 64 + j * 16 + c) * 64 + swg); \
    if (ST1) STG(A, m0, (s) + 1, 1, 0); \
    __builtin_amdgcn_s_barrier(); \
    PHASE_MFMA(0) \
    __builtin_amdgcn_s_barrier(); \
    __builtin_amdgcn_sched_barrier(0); \
    _Pragma("unroll") for (int i = 0; i < 4; ++i) af[i] = *(const s16x8*)(LA0 + (wm * 128 + (4 + i) * 16 + c) * 64 + swg); \
    if (ST2) STG(Bt, n0, (s) + 2, 0, 1); \
    __builtin_amdgcn_s_barrier(); \
    PHASE_MFMA(4) \
    asm volatile("s_waitcnt " VMID); \
    __builtin_amdgcn_s_barrier(); \
    __builtin_amdgcn_sched_barrier(0); \
    _Pragma("unroll") for (int i = 0; i < 4; ++i) af[i] = *(const s16x8*)(LA1 + (wm * 128 + i * 16 + c) * 64 + swg); \
    _Pragma("unroll") for (int j = 0; j < 4; ++j) bf[j] = *(const s16x8*)(LB1 + (wn * 64 + j * 16 + c) * 64 + swg); \
    if (ST3) STG(A, m0, (s) + 2, 0, 0); \
    __builtin_amdgcn_s_barrier(); \
    PHASE_MFMA(0) \
    __builtin_amdgcn_s_barrier(); \
    __builtin_amdgcn_sched_barrier(0); \
    _Pragma("unroll") for (int i = 0; i < 4; ++i) af[i] = *(const s16x8*)(LA1 + (wm * 128 + (4 + i) * 16 + c) * 64 + swg); \
    if (ST4) STG(Bt, n0, (s) + 2, 1, 1); \
    __builtin_amdgcn_s_barrier(); \
    PHASE_MFMA(4) \
    if (VEND) { asm volatile("s_waitcnt " VMID##_E); } \
    __builtin_amdgcn_s_barrier(); \
    __builtin_amdgcn_sched_barrier(0); \
} while (0)

#define VM10 "vmcnt(10)"
#define VM10_E "vmcnt(10)"
#define VM8 "vmcnt(8)"
#define VM8_E "vmcnt(4)"
#define VM0 "vmcnt(0)"
#define VM0_E "vmcnt(0)"

    for (int s = 0; s < 14; ++s) GSTEP(s, 1, 1, 1, 1, VM10, 1);
    GSTEP(14, 1, 0, 0, 0, VM8, 1);
    GSTEP(15, 0, 0, 0, 0, VM0, 0);

    const long mrow0 = m0 + wm * 128;
    const int ncol0 = (int)n0 + wn * 64;
    if (OM == 0) {
        if (ncol0 < 2048) {
#pragma unroll
            for (int j = 0; j < 4; ++j) {
                int n = ncol0 + j * 16 + c;
                float bv = bias[n];
#pragma unroll
                for (int i = 0; i < 8; ++i)
#pragma unroll
                    for (int r = 0; r < 4; ++r) {
                        long m = mrow0 + i * 16 + 4 * g + r;
                        qkb[m * 2048 + n] = f2b(acc[i][j][r] + bv);
                    }
            }
        } else {
#pragma unroll
            for (int j = 0; j < 4; ++j) {
                int n = ncol0 + j * 16 + c;
                float bv = bias[n];
                int h = (n - 2048) >> 6, hd = n & 63;
#pragma unroll
                for (int i = 0; i < 8; ++i) {
                    long m = mrow0 + i * 16 + 4 * g;
                    long bb = m >> 13, ss = m & 8191;
                    union { unsigned short sh[4]; unsigned long long u; } o;
#pragma unroll
                    for (int r = 0; r < 4; ++r) o.sh[r] = f2b(acc[i][j][r] + bv);
                    *(unsigned long long*)(vT + ((bb * 16 + h) * 64 + hd) * 8192 + ss) = o.u;
                }
            }
        }
    } else {
#pragma unroll
        for (int j = 0; j < 4; ++j) {
            int n = ncol0 + j * 16 + c;
            float bv = bias[n];
#pragma unroll
            for (int i = 0; i < 8; ++i)
#pragma unroll
                for (int r = 0; r < 4; ++r) {
                    long m = mrow0 + i * 16 + 4 * g + r;
                    Cf[m * 1024 + n] = acc[i][j][r] + bv;
                }
        }
    }
#undef STG
#undef PHASE_MFMA
#undef GSTEP
}

// ---------------- ring block attention (QBLK=128, 40KB LDS -> 4 blocks/CU) ----------------
// qkb: [B*S, 2048] bf16 (Q|K); vT: [(b*16+h)*64+hd][8192] bf16; out: [B*S,1024] bf16
__global__ __launch_bounds__(256, 4) void attn_kernel(const unsigned short* __restrict__ qkb,
                                                      const unsigned short* __restrict__ vT,
                                                      unsigned short* __restrict__ outp) {
    // KV[0..1]: K dbuf; KV[2..3]: V^T dbuf. Tile [64 rows][8x16B chunks], chunk cl holds cl^(row&7).
    // Pb[w]: per-wave P buffer [16 q][128B], byte off ^= (c&7)<<4 (qg-sequential reuse).
    __shared__ __align__(16) char KV[4][8192];
    __shared__ __align__(16) char Pb[4][2048];
    const int bid = blockIdx.x;
    const int wgid = (bid & 7) * 256 + (bid >> 3);  // XCD swizzle (2048 wgs)
    const int qt = wgid & 3;
    const int nblk = (wgid >> 2) & 15;
    const int h = (wgid >> 6) & 15;
    const int b = wgid >> 10;
    const int tid = threadIdx.x;
    const int w = tid >> 6, l = tid & 63;
    const int c = l & 15, g = l >> 4;

    const long qrow0 = (long)b * 8192 + nblk * 512 + qt * 128 + w * 32 + c;
    s16x8 qf[2][2];
#pragma unroll
    for (int qg = 0; qg < 2; ++qg) {
        const unsigned short* qp = qkb + (qrow0 + qg * 16) * 2048 + h * 64;
        qf[qg][0] = *(const s16x8*)(qp + g * 8);
        qf[qg][1] = *(const s16x8*)(qp + 32 + g * 8);
    }

    char* pw = Pb[w];
    const int psw = (c & 7) << 4;  // P-buffer XOR swizzle
    const float C2 = 0.125f * 1.44269504088896f;  // scale * log2(e)

    const int cl = tid & 7, rw = tid >> 3;
    const int sc = cl ^ (rw & 7);
    const int kb1 = (nblk + 1) & 15;
    const unsigned short* Kg0 = qkb + ((long)b * 8192 + nblk * 512 + rw) * 2048 + 1024 + h * 64 + sc * 8;
    const unsigned short* Kg1 = qkb + ((long)b * 8192 + kb1 * 512 + rw) * 2048 + 1024 + h * 64 + sc * 8;
    const unsigned short* Vg0 = vT + ((long)(b * 16 + h) * 64 + rw) * 8192 + nblk * 512 + sc * 8;
    const unsigned short* Vg1 = vT + ((long)(b * 16 + h) * 64 + rw) * 8192 + kb1 * 512 + sc * 8;

#define STAGE(tile) do { \
    const unsigned short* kn_ = (((tile) & 8) ? Kg1 : Kg0) + ((long)((tile) & 7) << 17); \
    const unsigned short* vn_ = (((tile) & 8) ? Vg1 : Vg0) + (((tile) & 7) << 6); \
    char* kd_ = KV[(tile) & 1] + tid * 16; \
    char* vd_ = KV[2 + ((tile) & 1)] + tid * 16; \
    async_copy16(kn_, kd_); \
    async_copy16(kn_ + 32L * 2048, kd_ + 4096); \
    async_copy16(vn_, vd_); \
    async_copy16(vn_ + 32L * 8192, vd_ + 4096); \
} while (0)

    float outv[2][16];
#pragma unroll
    for (int qg = 0; qg < 2; ++qg)
#pragma unroll
        for (int i = 0; i < 16; ++i) outv[qg][i] = 0.f;
    f32x4 oac[2][4];
#pragma unroll
    for (int qg = 0; qg < 2; ++qg)
#pragma unroll
        for (int i = 0; i < 4; ++i) oac[qg][i] = (f32x4){0.f, 0.f, 0.f, 0.f};
    float mrun[2] = {-3e38f, -3e38f}, lrun[2] = {0.f, 0.f};  // lrun per-lane partial

    const int ch0 = (g ^ (c & 7)) << 4;  // K/V tile read swizzle

    STAGE(0);

    for (int it = 0; it < 16; ++it) {
        if (it < 15) {
            STAGE(it + 1);
            asm volatile("s_waitcnt vmcnt(4)" ::: "memory");
        } else {
            asm volatile("s_waitcnt vmcnt(0)" ::: "memory");
        }
        __builtin_amdgcn_s_barrier();
        __builtin_amdgcn_sched_barrier(0);

        const char* Kc = KV[it & 1];
        const char* Vc = KV[2 + (it & 1)];

        // S^T = K @ Q^T : lane (c,g) holds S^T[key = kt*16 + 4g + r][q = c] per qg
        f32x4 sac[2][4];
#pragma unroll
        for (int qg = 0; qg < 2; ++qg)
#pragma unroll
            for (int i = 0; i < 4; ++i) sac[qg][i] = (f32x4){0.f, 0.f, 0.f, 0.f};
        __builtin_amdgcn_s_setprio(1);
#pragma unroll
        for (int kt = 0; kt < 4; ++kt) {
            const char* kr = Kc + (kt * 16 + c) * 128;
            s16x8 a0 = *(const s16x8*)(kr + ch0);
            s16x8 a1 = *(const s16x8*)(kr + (ch0 ^ 64));
            sac[0][kt] = __builtin_amdgcn_mfma_f32_16x16x32_bf16(a0, qf[0][0], sac[0][kt], 0, 0, 0);
            sac[0][kt] = __builtin_amdgcn_mfma_f32_16x16x32_bf16(a1, qf[0][1], sac[0][kt], 0, 0, 0);
            sac[1][kt] = __builtin_amdgcn_mfma_f32_16x16x32_bf16(a0, qf[1][0], sac[1][kt], 0, 0, 0);
            sac[1][kt] = __builtin_amdgcn_mfma_f32_16x16x32_bf16(a1, qf[1][1], sac[1][kt], 0, 0, 0);
        }
        __builtin_amdgcn_s_setprio(0);

        // per q-group: softmax -> P (swizzled wave-private LDS) -> PV  (qg-sequential P reuse)
#pragma unroll
        for (int qg = 0; qg < 2; ++qg) {
            // tree max over 16 regs
            float t0 = fmaxf(fmaxf(sac[qg][0][0], sac[qg][0][1]), fmaxf(sac[qg][0][2], sac[qg][0][3]));
            float t1 = fmaxf(fmaxf(sac[qg][1][0], sac[qg][1][1]), fmaxf(sac[qg][1][2], sac[qg][1][3]));
            float t2 = fmaxf(fmaxf(sac[qg][2][0], sac[qg][2][1]), fmaxf(sac[qg][2][2], sac[qg][2][3]));
            float t3 = fmaxf(fmaxf(sac[qg][3][0], sac[qg][3][1]), fmaxf(sac[qg][3][2], sac[qg][3][3]));
            float mx = fmaxf(fmaxf(t0, t1), fmaxf(t2, t3));
            mx = fmaxf(mx, __shfl_xor(mx, 16, 64));
            mx = fmaxf(mx, __shfl_xor(mx, 32, 64));
            // defer-max (T13): rescale only if some row grew past threshold (P bounded by 2^8)
            if (!__all((mx - mrun[qg]) * C2 <= 8.0f)) {
                float mnew = fmaxf(mrun[qg], mx);
                float alpha = exp2f((mrun[qg] - mnew) * C2);
                lrun[qg] *= alpha;
#pragma unroll
                for (int i = 0; i < 4; ++i) oac[qg][i] *= alpha;
                mrun[qg] = mnew;
            }
            const float m = mrun[qg];
            float ls = 0.f;
#pragma unroll
            for (int kt = 0; kt < 4; ++kt) {
                union { unsigned short sh[4]; unsigned long long u; } pk;
#pragma unroll
                for (int r = 0; r < 4; ++r) {
                    float e = exp2f((sac[qg][kt][r] - m) * C2);
                    ls += e;
                    pk.sh[r] = f2b(e);
                }
                *(unsigned long long*)(pw + c * 128 + ((kt * 32 + g * 8) ^ psw)) = pk.u;
            }
            lrun[qg] += ls;

            // PV for this qg: O^T += V^T @ P^T
            __builtin_amdgcn_s_setprio(1);
#pragma unroll
            for (int kf = 0; kf < 2; ++kf) {
                s16x8 pf = *(const s16x8*)(pw + c * 128 + ((kf * 64 + g * 16) ^ psw));
#pragma unroll
                for (int ht = 0; ht < 4; ++ht) {
                    s16x8 vf = *(const s16x8*)(Vc + (ht * 16 + c) * 128 + (ch0 ^ (kf << 6)));
                    oac[qg][ht] = __builtin_amdgcn_mfma_f32_16x16x32_bf16(vf, pf, oac[qg][ht], 0, 0, 0);
                }
            }
            __builtin_amdgcn_s_setprio(0);
        }

        if ((it & 7) == 7) {  // pass boundary: reduce lrun across lanes, fold normalized result
#pragma unroll
            for (int qg = 0; qg < 2; ++qg) {
                float lt = lrun[qg];
                lt += __shfl_xor(lt, 16, 64);
                lt += __shfl_xor(lt, 32, 64);
                float inv = 1.f / lt;
#pragma unroll
                for (int i = 0; i < 16; ++i) outv[qg][i] += oac[qg][i >> 2][i & 3] * inv;
#pragma unroll
                for (int i = 0; i < 4; ++i) oac[qg][i] = (f32x4){0.f, 0.f, 0.f, 0.f};
                mrun[qg] = -3e38f;
                lrun[qg] = 0.f;
            }
        }
        __builtin_amdgcn_sched_barrier(0);
        __builtin_amdgcn_s_barrier();  // all waves done reading buf[it&1]
        __builtin_amdgcn_sched_barrier(0);
    }
#undef STAGE

    // lane holds O^T[hd = ht*16 + 4g + r][q = c] per qg; 8B packed stores
#pragma unroll
    for (int qg = 0; qg < 2; ++qg) {
        unsigned short* op = outp + (qrow0 + qg * 16) * 1024 + h * 64;
#pragma unroll
        for (int ht = 0; ht < 4; ++ht) {
            union { unsigned short sh[4]; unsigned long long u; } o;
#pragma unroll
            for (int r = 0; r < 4; ++r) o.sh[r] = f2b(outv[qg][ht * 4 + r]);
            *(unsigned long long*)(op + ht * 16 + 4 * g) = o.u;
        }
    }
}

extern "C" void kernel_launch(void* const* d_in, const int* in_sizes, int n_in,
                              void* d_out, int out_size, void* d_ws, size_t ws_size,
                              hipStream_t stream) {
    const float* x    = (const float*)d_in[0];
    const float* Wqkv = (const float*)d_in[1];
    const float* bqkv = (const float*)d_in[2];
    const float* Wout = (const float*)d_in[3];
    const float* bout = (const float*)d_in[4];
    float* out = (float*)d_out;

    char* ws = (char*)d_ws;
    unsigned short* xbf   = (unsigned short*)ws;
    unsigned short* wqkvT = (unsigned short*)(ws + 33554432);
    unsigned short* woutT = (unsigned short*)(ws + 39845888);
    unsigned short* qkb   = (unsigned short*)(ws + 41943040);
    unsigned short* vT    = (unsigned short*)(ws + 109051904);
    unsigned short* attn  = xbf;  // alias: xbf dead after QKV GEMM

    cvt_x_kernel<<<8192, 256, 0, stream>>>(x, xbf);
    cvt_wT_kernel<<<(1024 / 64) * (3072 / 64), 256, 0, stream>>>(Wqkv, wqkvT, 1024, 3072);
    cvt_wT_kernel<<<(1024 / 64) * (1024 / 64), 256, 0, stream>>>(Wout, woutT, 1024, 1024);
    gemm256_kernel<0><<<64 * 12, 512, 0, stream>>>(xbf, wqkvT, bqkv, qkb, vT, nullptr, 12);
    attn_kernel<<<2048, 256, 0, stream>>>(qkb, vT, attn);
    gemm256_kernel<1><<<64 * 4, 512, 0, stream>>>(attn, woutT, bout, nullptr, nullptr, out, 4);
}